// Round 2
// baseline (82.701 us; speedup 1.0000x reference)
//
#include <hip/hip_runtime.h>
#include <cstdint>
#include <cstddef>

// Dims (fixed by the reference)
#define R_   16
#define NH_  8
#define D_   32
#define C_   256
#define B_   16
#define XY_  1024      // 32*32
#define RH_  128       // R_*NH_
#define KD_  4096      // R_*NH_*D_
#define TP   16        // positions per block in main kernel
#define ZSTR 20        // padded LDS stride (floats), 16B aligned
#define LSTR 20

// ---------------------------------------------------------------------------
// Precompute: per (r,h) block computes
//   k[d] = Wk[r,h*D+d,:]·rims[r,:] + bk,   v[d] likewise (4 lanes per dot)
//   WLt[c][rh] = sum_d k[d]*Wq[rh*D+d, c]        (transposed for GEMM1 loads)
//   U[rh][c]   = sum_d v[d]*Wm[c, rh*D+d]
//   c0[rh]     = sum_d k[d]*bq[rh*D+d]
// ---------------------------------------------------------------------------
__global__ __launch_bounds__(256)
void rims_precompute(const float* __restrict__ rims,
                     const float* __restrict__ Wk,
                     const float* __restrict__ bk,
                     const float* __restrict__ Wv,
                     const float* __restrict__ bv,
                     const float* __restrict__ Wq,
                     const float* __restrict__ bq,
                     const float* __restrict__ Wm,
                     float* __restrict__ WLt,
                     float* __restrict__ Uo,
                     float* __restrict__ c0o)
{
    const int rh  = blockIdx.x;        // 0..127
    const int r   = rh >> 3;
    const int h   = rh & 7;
    const int tid = threadIdx.x;

    __shared__ float ks[D_];
    __shared__ float vs[D_];

    // ---- k/v dot products: 64 dots, 4 lanes each (64-elem chunks) ----
    {
        const int idx  = tid >> 2;         // 0..63 : (isv, d)
        const int part = tid & 3;
        const int d    = idx & (D_ - 1);
        const bool isv = (idx >= D_);
        const float* Wrow = (isv ? Wv : Wk) + ((size_t)r * 256 + h * D_ + d) * C_ + part * 64;
        const float* rr   = rims + r * C_ + part * 64;
        float a0 = 0.f, a1 = 0.f, a2 = 0.f, a3 = 0.f;
        #pragma unroll
        for (int j = 0; j < 16; ++j) {
            const float4 w = *reinterpret_cast<const float4*>(Wrow + j * 4);
            const float4 x = *reinterpret_cast<const float4*>(rr + j * 4);
            a0 = fmaf(w.x, x.x, a0); a1 = fmaf(w.y, x.y, a1);
            a2 = fmaf(w.z, x.z, a2); a3 = fmaf(w.w, x.w, a3);
        }
        float acc = (a0 + a1) + (a2 + a3);
        acc += __shfl_xor(acc, 1);
        acc += __shfl_xor(acc, 2);
        if (part == 0) {
            const float val = acc + (isv ? bv : bk)[r * 256 + h * D_ + d];
            if (isv) vs[d] = val; else ks[d] = val;
        }
    }
    __syncthreads();

    // ---- fold k into Wq rows, v into Wm columns ----
    {
        const int c = tid;                 // 0..255
        float wl = 0.f, uu = 0.f;
        const float* wqp = Wq + (size_t)rh * D_ * C_ + c;
        const float* wmp = Wm + (size_t)c * KD_ + rh * D_;
        #pragma unroll
        for (int d4 = 0; d4 < D_; d4 += 4) {
            const float4 wm4 = *reinterpret_cast<const float4*>(wmp + d4);
            wl = fmaf(ks[d4 + 0], wqp[(d4 + 0) * C_], wl);
            wl = fmaf(ks[d4 + 1], wqp[(d4 + 1) * C_], wl);
            wl = fmaf(ks[d4 + 2], wqp[(d4 + 2) * C_], wl);
            wl = fmaf(ks[d4 + 3], wqp[(d4 + 3) * C_], wl);
            uu = fmaf(vs[d4 + 0], wm4.x, uu);
            uu = fmaf(vs[d4 + 1], wm4.y, uu);
            uu = fmaf(vs[d4 + 2], wm4.z, uu);
            uu = fmaf(vs[d4 + 3], wm4.w, uu);
        }
        WLt[c * RH_ + rh] = wl;            // transposed layout [c][rh]
        Uo[rh * C_ + c]   = uu;            // row-major [rh][c]
    }

    // ---- c0[rh] = k·bq slice (wave reduce over 32 lanes) ----
    if (tid < D_) {
        float s = ks[tid] * bq[rh * D_ + tid];
        s += __shfl_xor(s, 1);  s += __shfl_xor(s, 2);  s += __shfl_xor(s, 4);
        s += __shfl_xor(s, 8);  s += __shfl_xor(s, 16);
        if (tid == 0) c0o[rh] = s;
    }
}

// ---------------------------------------------------------------------------
// Main fused kernel: per block = 16 spatial positions of one batch image.
//   stage Z-tile (256 x 16) -> LDS
//   GEMM1: L[rh][p] = WLt[:,rh]·Zs[:,p] + c0[rh]          (128x16, K=256)
//   softmax over r (stride NH_ rows) per (h,p)
//   GEMM2: out[c][p] = U[rh][c]·A[rh][p] + bm[c]          (256x16, K=128)
// LDS = 30.7 KB -> grid 1024 gives 4 blocks/CU = 16 waves/CU (50% occ).
// ---------------------------------------------------------------------------
__global__ __launch_bounds__(256, 4)
void rims_main(const float* __restrict__ z,
               const float* __restrict__ WLt,
               const float* __restrict__ Uo,
               const float* __restrict__ c0v,
               const float* __restrict__ bm,
               float* __restrict__ out)
{
    __shared__ float Zs[C_ * ZSTR];    // 20480 B
    __shared__ float Ls[RH_ * LSTR];   // 10240 B

    const int tid = threadIdx.x;
    const int blk = blockIdx.x;        // 1024 blocks
    const int b   = blk >> 6;          // 64 blocks per batch image
    const int xy0 = (blk & 63) * TP;
    const float* zb = z + (size_t)b * C_ * XY_ + xy0;

    // ---- stage Z tile: thread -> (c = tid>>2 + 64i, p4 = (tid&3)*4) ----
    {
        const int p4 = (tid & 3) << 2;
        const int c0 = tid >> 2;       // 0..63
        #pragma unroll
        for (int i = 0; i < 4; ++i) {
            const int c = c0 + (i << 6);
            const float4 v = *reinterpret_cast<const float4*>(zb + (size_t)c * XY_ + p4);
            *reinterpret_cast<float4*>(&Zs[c * ZSTR + p4]) = v;
        }
    }
    __syncthreads();

    // ---- GEMM1: thread computes 4rh x 2p over K=256 ----
    {
        const int p0  = (tid & 7) << 1;    // 0..14
        const int rh0 = (tid >> 3) << 2;   // 0..124
        float a00 = 0.f, a01 = 0.f, a10 = 0.f, a11 = 0.f;
        float a20 = 0.f, a21 = 0.f, a30 = 0.f, a31 = 0.f;
        #pragma unroll 8
        for (int c = 0; c < C_; ++c) {
            const float4 wv = *reinterpret_cast<const float4*>(WLt + (c << 7) + rh0);
            const float2 zv = *reinterpret_cast<const float2*>(&Zs[c * ZSTR + p0]);
            a00 = fmaf(wv.x, zv.x, a00); a01 = fmaf(wv.x, zv.y, a01);
            a10 = fmaf(wv.y, zv.x, a10); a11 = fmaf(wv.y, zv.y, a11);
            a20 = fmaf(wv.z, zv.x, a20); a21 = fmaf(wv.z, zv.y, a21);
            a30 = fmaf(wv.w, zv.x, a30); a31 = fmaf(wv.w, zv.y, a31);
        }
        const float c0a = c0v[rh0 + 0], c0b = c0v[rh0 + 1];
        const float c0c = c0v[rh0 + 2], c0d = c0v[rh0 + 3];
        *reinterpret_cast<float2*>(&Ls[(rh0 + 0) * LSTR + p0]) = make_float2(a00 + c0a, a01 + c0a);
        *reinterpret_cast<float2*>(&Ls[(rh0 + 1) * LSTR + p0]) = make_float2(a10 + c0b, a11 + c0b);
        *reinterpret_cast<float2*>(&Ls[(rh0 + 2) * LSTR + p0]) = make_float2(a20 + c0c, a21 + c0c);
        *reinterpret_cast<float2*>(&Ls[(rh0 + 3) * LSTR + p0]) = make_float2(a30 + c0d, a31 + c0d);
    }
    __syncthreads();

    // ---- softmax over r (16 values, stride NH_ rows) per (h,p) ----
    if (tid < 128) {
        const int h = tid >> 4;        // 0..7
        const int p = tid & 15;        // 0..15
        float vals[R_];
        float m = -1e30f;
        #pragma unroll
        for (int r = 0; r < R_; ++r) {
            vals[r] = Ls[(r * NH_ + h) * LSTR + p];
            m = fmaxf(m, vals[r]);
        }
        float s = 0.f;
        #pragma unroll
        for (int r = 0; r < R_; ++r) { vals[r] = __expf(vals[r] - m); s += vals[r]; }
        const float inv = 1.f / s;
        #pragma unroll
        for (int r = 0; r < R_; ++r) Ls[(r * NH_ + h) * LSTR + p] = vals[r] * inv;
    }
    __syncthreads();

    // ---- GEMM2: thread computes 8c x 2p over K=128 ----
    {
        const int p0 = (tid & 7) << 1;     // 0..14
        const int cb = (tid >> 3) << 3;    // 0..248
        float acc[8][2];
        #pragma unroll
        for (int j = 0; j < 8; ++j) { acc[j][0] = 0.f; acc[j][1] = 0.f; }

        #pragma unroll 8
        for (int rh = 0; rh < RH_; ++rh) {
            const float2 av = *reinterpret_cast<const float2*>(&Ls[rh * LSTR + p0]);
            const float4 u0 = *reinterpret_cast<const float4*>(Uo + (rh << 8) + cb);
            const float4 u1 = *reinterpret_cast<const float4*>(Uo + (rh << 8) + cb + 4);
            const float uv[8] = {u0.x, u0.y, u0.z, u0.w, u1.x, u1.y, u1.z, u1.w};
            #pragma unroll
            for (int j = 0; j < 8; ++j) {
                acc[j][0] = fmaf(uv[j], av.x, acc[j][0]);
                acc[j][1] = fmaf(uv[j], av.y, acc[j][1]);
            }
        }

        float* ob = out + (size_t)b * C_ * XY_ + xy0;
        #pragma unroll
        for (int j = 0; j < 8; ++j) {
            const float bb = bm[cb + j];
            *reinterpret_cast<float2*>(ob + (size_t)(cb + j) * XY_ + p0) =
                make_float2(acc[j][0] + bb, acc[j][1] + bb);
        }
    }
}

// ---------------------------------------------------------------------------
extern "C" void kernel_launch(void* const* d_in, const int* in_sizes, int n_in,
                              void* d_out, int out_size, void* d_ws, size_t ws_size,
                              hipStream_t stream)
{
    const float* z    = (const float*)d_in[0];
    const float* rims = (const float*)d_in[1];
    const float* Wk   = (const float*)d_in[2];
    const float* bk   = (const float*)d_in[3];
    const float* Wv   = (const float*)d_in[4];
    const float* bv   = (const float*)d_in[5];
    const float* Wq   = (const float*)d_in[6];
    const float* bq   = (const float*)d_in[7];
    const float* Wm   = (const float*)d_in[8];
    const float* bm   = (const float*)d_in[9];
    float* out = (float*)d_out;

    // workspace layout: WLt (C_*RH_) | U (RH_*C_) | c0 (RH_)
    float* WLt = (float*)d_ws;
    float* Uo  = WLt + C_ * RH_;
    float* c0o = Uo + RH_ * C_;

    rims_precompute<<<RH_, 256, 0, stream>>>(rims, Wk, bk, Wv, bv, Wq, bq, Wm,
                                             WLt, Uo, c0o);
    rims_main<<<(B_ * XY_) / TP, 256, 0, stream>>>(z, WLt, Uo, c0o, bm, out);
}

// Round 3
// 60.452 us; speedup vs baseline: 1.3680x; 1.3680x over previous
//
#include <hip/hip_runtime.h>
#include <cstdint>
#include <cstddef>

// Dims (fixed by the reference)
#define R_   16
#define NH_  8
#define D_   32
#define C_   256
#define B_   16
#define XY_  1024      // 32*32
#define RH_  128       // R_*NH_
#define KD_  4096      // R_*NH_*D_
#define TP   64        // positions per block (lane = position)

// ---------------------------------------------------------------------------
// Precompute: per (r,h) block computes
//   k[d] = Wk[r,h*D+d,:]·rims[r,:] + bk,   v[d] likewise (4 lanes per dot)
//   WLt[c][rh] = sum_d k[d]*Wq[rh*D+d, c]        (transposed: [c][rh])
//   U[rh][c]   = sum_d v[d]*Wm[c, rh*D+d]        (row-major: [rh][c])
//   c0[rh]     = sum_d k[d]*bq[rh*D+d]
// ---------------------------------------------------------------------------
__global__ __launch_bounds__(256)
void rims_precompute(const float* __restrict__ rims,
                     const float* __restrict__ Wk,
                     const float* __restrict__ bk,
                     const float* __restrict__ Wv,
                     const float* __restrict__ bv,
                     const float* __restrict__ Wq,
                     const float* __restrict__ bq,
                     const float* __restrict__ Wm,
                     float* __restrict__ WLt,
                     float* __restrict__ Uo,
                     float* __restrict__ c0o)
{
    const int rh  = blockIdx.x;        // 0..127
    const int r   = rh >> 3;
    const int h   = rh & 7;
    const int tid = threadIdx.x;

    __shared__ float ks[D_];
    __shared__ float vs[D_];

    // ---- k/v dot products: 64 dots, 4 lanes each (64-elem chunks) ----
    {
        const int idx  = tid >> 2;         // 0..63 : (isv, d)
        const int part = tid & 3;
        const int d    = idx & (D_ - 1);
        const bool isv = (idx >= D_);
        const float* Wrow = (isv ? Wv : Wk) + ((size_t)r * 256 + h * D_ + d) * C_ + part * 64;
        const float* rr   = rims + r * C_ + part * 64;
        float a0 = 0.f, a1 = 0.f, a2 = 0.f, a3 = 0.f;
        #pragma unroll
        for (int j = 0; j < 16; ++j) {
            const float4 w = *reinterpret_cast<const float4*>(Wrow + j * 4);
            const float4 x = *reinterpret_cast<const float4*>(rr + j * 4);
            a0 = fmaf(w.x, x.x, a0); a1 = fmaf(w.y, x.y, a1);
            a2 = fmaf(w.z, x.z, a2); a3 = fmaf(w.w, x.w, a3);
        }
        float acc = (a0 + a1) + (a2 + a3);
        acc += __shfl_xor(acc, 1);
        acc += __shfl_xor(acc, 2);
        if (part == 0) {
            const float val = acc + (isv ? bv : bk)[r * 256 + h * D_ + d];
            if (isv) vs[d] = val; else ks[d] = val;
        }
    }
    __syncthreads();

    // ---- fold k into Wq rows, v into Wm columns ----
    {
        const int c = tid;                 // 0..255
        float wl = 0.f, uu = 0.f;
        const float* wqp = Wq + (size_t)rh * D_ * C_ + c;
        const float* wmp = Wm + (size_t)c * KD_ + rh * D_;
        #pragma unroll
        for (int d4 = 0; d4 < D_; d4 += 4) {
            const float4 wm4 = *reinterpret_cast<const float4*>(wmp + d4);
            wl = fmaf(ks[d4 + 0], wqp[(d4 + 0) * C_], wl);
            wl = fmaf(ks[d4 + 1], wqp[(d4 + 1) * C_], wl);
            wl = fmaf(ks[d4 + 2], wqp[(d4 + 2) * C_], wl);
            wl = fmaf(ks[d4 + 3], wqp[(d4 + 3) * C_], wl);
            uu = fmaf(vs[d4 + 0], wm4.x, uu);
            uu = fmaf(vs[d4 + 1], wm4.y, uu);
            uu = fmaf(vs[d4 + 2], wm4.z, uu);
            uu = fmaf(vs[d4 + 3], wm4.w, uu);
        }
        WLt[c * RH_ + rh] = wl;            // [c][rh]
        Uo[rh * C_ + c]   = uu;            // [rh][c]
    }

    // ---- c0[rh] = k·bq slice (wave reduce over 32 lanes) ----
    if (tid < D_) {
        float s = ks[tid] * bq[rh * D_ + tid];
        s += __shfl_xor(s, 1);  s += __shfl_xor(s, 2);  s += __shfl_xor(s, 4);
        s += __shfl_xor(s, 8);  s += __shfl_xor(s, 16);
        if (tid == 0) c0o[rh] = s;
    }
}

// ---------------------------------------------------------------------------
// Main fused kernel. Block = 512 threads (8 waves), 64 positions, lane = p.
//   stage z[256][64] -> LDS (once, float4 coalesced)
//   GEMM1: wave w owns rh in [16w,16w+16): acc[j] += WLt[c][rh]*Zs[c][lane]
//          weight address is wave-uniform -> scalar loads (s_load pipe)
//   softmax over r per (h=w, p=lane), stride-1 LDS rows
//   GEMM2: wave w owns c in [32w,32w+32): out[c][p] = U[rh][c]*A[rh][p]
// All LDS accesses are lane-stride-1 (2-way bank alias only = free).
// ---------------------------------------------------------------------------
__global__ __launch_bounds__(512, 2)
void rims_main(const float* __restrict__ z,
               const float* __restrict__ WLt,
               const float* __restrict__ Uo,
               const float* __restrict__ c0v,
               const float* __restrict__ bm,
               float* __restrict__ out)
{
    __shared__ float Zs[C_ * TP];    // 64 KB  [c][p]
    __shared__ float Ls[RH_ * TP];   // 32 KB  [rh][p]

    const int tid  = threadIdx.x;
    const int lane = tid & 63;
    const int w    = __builtin_amdgcn_readfirstlane(tid >> 6);  // wave id 0..7 (uniform)
    const int blk  = blockIdx.x;     // 256 blocks
    const int b    = blk >> 4;       // 16 blocks per image
    const int xy0  = (blk & 15) * TP;
    const float* zb = z + ((size_t)b * C_) * XY_ + xy0;

    // ---- stage z tile: 512 threads x 8 float4 = 64 KB ----
    {
        const int p4 = (tid & 15) << 2;
        const int c0 = tid >> 4;         // 0..31
        #pragma unroll
        for (int i = 0; i < 8; ++i) {
            const int c = c0 + (i << 5);
            *reinterpret_cast<float4*>(&Zs[c * TP + p4]) =
                *reinterpret_cast<const float4*>(zb + (size_t)c * XY_ + p4);
        }
    }
    __syncthreads();

    // ---- GEMM1: 16 rh rows per wave, K = 256 ----
    {
        const int rh0 = w << 4;
        float acc[16];
        #pragma unroll
        for (int j = 0; j < 16; ++j) acc[j] = 0.f;
        const float* wp = WLt + rh0;              // row stride RH_
        #pragma unroll 4
        for (int c = 0; c < C_; ++c) {
            const float zv = Zs[c * TP + lane];
            #pragma unroll
            for (int j = 0; j < 16; ++j)
                acc[j] = fmaf(wp[c * RH_ + j], zv, acc[j]);   // uniform weight addr
        }
        #pragma unroll
        for (int j = 0; j < 16; ++j)
            Ls[(rh0 + j) * TP + lane] = acc[j] + c0v[rh0 + j];
    }
    __syncthreads();

    // ---- softmax over r (16 rims) per (h = w, p = lane) ----
    {
        float vals[R_];
        float m = -1e30f;
        #pragma unroll
        for (int r = 0; r < R_; ++r) {
            vals[r] = Ls[(r * NH_ + w) * TP + lane];
            m = fmaxf(m, vals[r]);
        }
        float s = 0.f;
        #pragma unroll
        for (int r = 0; r < R_; ++r) { vals[r] = __expf(vals[r] - m); s += vals[r]; }
        const float inv = 1.f / s;
        #pragma unroll
        for (int r = 0; r < R_; ++r) Ls[(r * NH_ + w) * TP + lane] = vals[r] * inv;
    }
    __syncthreads();

    // ---- GEMM2: 32 c rows per wave, K = 128 ----
    {
        const int c0 = w << 5;
        float acc[32];
        #pragma unroll
        for (int j = 0; j < 32; ++j) acc[j] = 0.f;
        const float* up = Uo + c0;                // row stride C_
        #pragma unroll 2
        for (int rh = 0; rh < RH_; ++rh) {
            const float av = Ls[rh * TP + lane];
            #pragma unroll
            for (int j = 0; j < 32; ++j)
                acc[j] = fmaf(up[rh * C_ + j], av, acc[j]);   // uniform weight addr
        }
        float* ob = out + ((size_t)b * C_ + c0) * XY_ + xy0;
        #pragma unroll
        for (int j = 0; j < 32; ++j)
            ob[(size_t)j * XY_ + lane] = acc[j] + bm[c0 + j];
    }
}

// ---------------------------------------------------------------------------
extern "C" void kernel_launch(void* const* d_in, const int* in_sizes, int n_in,
                              void* d_out, int out_size, void* d_ws, size_t ws_size,
                              hipStream_t stream)
{
    const float* z    = (const float*)d_in[0];
    const float* rims = (const float*)d_in[1];
    const float* Wk   = (const float*)d_in[2];
    const float* bk   = (const float*)d_in[3];
    const float* Wv   = (const float*)d_in[4];
    const float* bv   = (const float*)d_in[5];
    const float* Wq   = (const float*)d_in[6];
    const float* bq   = (const float*)d_in[7];
    const float* Wm   = (const float*)d_in[8];
    const float* bm   = (const float*)d_in[9];
    float* out = (float*)d_out;

    // workspace layout: WLt (C_*RH_) | U (RH_*C_) | c0 (RH_)
    float* WLt = (float*)d_ws;
    float* Uo  = WLt + C_ * RH_;
    float* c0o = Uo + RH_ * C_;

    rims_precompute<<<RH_, 256, 0, stream>>>(rims, Wk, bk, Wv, bv, Wq, bq, Wm,
                                             WLt, Uo, c0o);
    rims_main<<<(B_ * XY_) / TP, 512, 0, stream>>>(z, WLt, Uo, c0o, bm, out);
}